// Round 1
// baseline (179.919 us; speedup 1.0000x reference)
//
#include <hip/hip_runtime.h>
#include <stdint.h>

typedef unsigned short u16;
typedef unsigned int   u32;
typedef __attribute__((ext_vector_type(8))) short  bf16x8;
typedef __attribute__((ext_vector_type(4))) float  f32x4;
typedef __attribute__((ext_vector_type(4))) u32    u32x4;
typedef __attribute__((ext_vector_type(2))) u32    u32x2;

#define L_SEQ 2048
#define DMODEL 256
// B*H = 32, rows = 65536

// round-to-nearest-even f32 -> bf16
__device__ __forceinline__ u16 f2bf(float x){
  u32 u = __float_as_uint(x);
  return (u16)((u + 0x7FFFu + ((u >> 16) & 1u)) >> 16);
}

__device__ __forceinline__ void gload_lds16(const void* g, void* l){
  __builtin_amdgcn_global_load_lds(
      (const __attribute__((address_space(1))) u32*)g,
      (__attribute__((address_space(3))) u32*)l, 16, 0, 0);
}

// ---------------- xPos tables: [n][half=128] f32, 4 tables ----------------
__global__ void k_tables(float* __restrict__ tqc, float* __restrict__ tqs,
                         float* __restrict__ tkc, float* __restrict__ tks){
  int idx = blockIdx.x * 256 + threadIdx.x;     // 2048*128 = 262144
  int n = idx >> 7, i = idx & 127;
  float fn = (float)n, fi = (float)i;
  float invf = exp2f(-(fi * (1.0f/128.0f)) * 13.2877124f);   // 10000^(-i/128)
  float ang = fn * invf;
  float s = sinf(ang), c = cosf(ang);
  float sv = (2.0f * fi + 102.4f) * (1.0f / 358.4f);
  float sc = exp2f((fn * (1.0f/512.0f)) * log2f(sv));
  tqc[idx] = c * sc;  tqs[idx] = s * sc;
  float inv = 1.0f / sc;
  tkc[idx] = c * inv; tks[idx] = s * inv;
}

// ---------------- W^T bf16: wt[w][c][k] = W_w[k][c] ----------------
__global__ void k_wt(const float* __restrict__ wq, const float* __restrict__ wk,
                     const float* __restrict__ wv, u16* __restrict__ wt){
  int idx = blockIdx.x * 256 + threadIdx.x;     // 3*65536
  int w = idx >> 16, r = idx & 65535;
  int c = r >> 8, k = r & 255;
  const float* src = (w == 0) ? wq : ((w == 1) ? wk : wv);
  wt[idx] = f2bf(src[k * 256 + c]);
}

// ---------------- fused projection + xPos (+ V transpose) ----------------
// grid (512 row-tiles, 3 weights), block 512. Tile: 128 rows x 256 cols.
__global__ __launch_bounds__(512) void k_proj(
    const float* __restrict__ X, const u16* __restrict__ Wt,
    const float* __restrict__ tqc, const float* __restrict__ tqs,
    const float* __restrict__ tkc, const float* __restrict__ tks,
    u16* __restrict__ Qx, u16* __restrict__ Kx, u16* __restrict__ VT)
{
  __shared__ u16 ldsX[128 * 256];               // 64 KiB, chunk-swizzled
  const int rt = blockIdx.x;
  const int wsel = blockIdx.y;
  const int tid = threadIdx.x;
  const int lane = tid & 63, w = tid >> 6;
  const int h = lane >> 4, l15 = lane & 15;
  const int row0 = rt * 128;

  // stage X tile as bf16 (swizzle: chunk ^= row&7, 16B chunks)
  {
    int r = tid >> 2;            // 0..127
    int seg = tid & 3;           // 64 f32 each
    const float4* src = (const float4*)(X + (size_t)(row0 + r) * 256 + seg * 64);
#pragma unroll
    for (int cc = 0; cc < 8; ++cc){
      float4 a = src[cc * 2 + 0];
      float4 b = src[cc * 2 + 1];
      u32 d0 = (u32)f2bf(a.x) | ((u32)f2bf(a.y) << 16);
      u32 d1 = (u32)f2bf(a.z) | ((u32)f2bf(a.w) << 16);
      u32 d2 = (u32)f2bf(b.x) | ((u32)f2bf(b.y) << 16);
      u32 d3 = (u32)f2bf(b.z) | ((u32)f2bf(b.w) << 16);
      int chunk = seg * 8 + cc;
      int sw = chunk ^ (r & 7);
      u32x4 v; v.x = d0; v.y = d1; v.z = d2; v.w = d3;
      *(u32x4*)((char*)ldsX + r * 512 + sw * 16) = v;
    }
  }
  __syncthreads();

  const int wr = w >> 2, wc = w & 3;
  f32x4 acc[4][4] = {};
  const u16* wbase = Wt + wsel * 65536;

#pragma unroll
  for (int kb = 0; kb < 8; ++kb){
    bf16x8 a[4], b[4];
#pragma unroll
    for (int rti = 0; rti < 4; ++rti){
      int r = wr * 64 + rti * 16 + l15;
      int chunk = kb * 4 + h;
      int sw = chunk ^ (r & 7);
      a[rti] = *(const bf16x8*)((const char*)ldsX + r * 512 + sw * 16);
    }
#pragma unroll
    for (int cti = 0; cti < 4; ++cti){
      int col = wc * 64 + cti * 16 + l15;
      b[cti] = *(const bf16x8*)(wbase + col * 256 + kb * 32 + h * 8);
    }
#pragma unroll
    for (int rti = 0; rti < 4; ++rti)
#pragma unroll
      for (int cti = 0; cti < 4; ++cti)
        acc[rti][cti] = __builtin_amdgcn_mfma_f32_16x16x32_bf16(
            a[rti], b[cti], acc[rti][cti], 0, 0, 0);
  }

  if (wsel == 2){
    // V: write transposed VT[bh][d][pos], 8B contiguous per lane
#pragma unroll
    for (int rti = 0; rti < 4; ++rti){
      int grow = row0 + wr * 64 + rti * 16 + h * 4;
      int bh = grow >> 11;
      int pos = grow & 2047;
#pragma unroll
      for (int cti = 0; cti < 4; ++cti){
        int d = wc * 64 + cti * 16 + l15;
        f32x4 v = acc[rti][cti];
        u32x2 p;
        p.x = (u32)f2bf(v.x) | ((u32)f2bf(v.y) << 16);
        p.y = (u32)f2bf(v.z) | ((u32)f2bf(v.w) << 16);
        *(u32x2*)(VT + ((size_t)bh * DMODEL + d) * 2048 + pos) = p;
      }
    }
  } else {
    const float* tc = (wsel == 0) ? tqc : tkc;
    const float* ts = (wsel == 0) ? tqs : tks;
    u16* Od = (wsel == 0) ? Qx : Kx;
#pragma unroll
    for (int rti = 0; rti < 4; ++rti){
#pragma unroll
      for (int cti = 0; cti < 4; ++cti){
        int d = wc * 64 + cti * 16 + l15;
        int hi = d >> 1;
        float sgn = (d & 1) ? 1.0f : -1.0f;
        f32x4 v = acc[rti][cti];
#pragma unroll
        for (int r = 0; r < 4; ++r){
          int grow = row0 + wr * 64 + rti * 16 + h * 4 + r;
          int pos = grow & 2047;
          float x = v[r];
          float px = __shfl_xor(x, 1, 64);          // rotate partner (d^1)
          float cv = tc[pos * 128 + hi];
          float svl = ts[pos * 128 + hi];
          Od[(size_t)grow * 256 + d] = f2bf(x * cv + sgn * px * svl);
        }
      }
    }
  }
}

// ---------------- banded decayed attention ----------------
// grid 512 = 32 bh * 16 n-chunks(128). block 512 (8 waves x 16 rows).
__global__ __launch_bounds__(512) void k_attn(
    const u16* __restrict__ Qx, const u16* __restrict__ Kx,
    const u16* __restrict__ VT, float* __restrict__ out)
{
  __shared__ char smem[65536];
  u16* ldsK = (u16*)smem;                 // [64 m][256 d] bf16, swizzled
  u16* ldsV = (u16*)(smem + 32768);       // [256 d][64 m] bf16, swizzled

  const int bid = blockIdx.x;
  const int bh = bid >> 4, i = bid & 15;
  const int tid = threadIdx.x;
  const int lane = tid & 63, w = tid >> 6;
  const int h = lane >> 4, l15 = lane & 15;
  const int n_g = i * 128 + w * 16 + l15;

  // Q B-fragments (k-contiguous from row n_g)
  bf16x8 q[8];
  const u16* qbase = Qx + ((size_t)bh * 2048 + n_g) * 256;
#pragma unroll
  for (int kb = 0; kb < 8; ++kb)
    q[kb] = *(const bf16x8*)(qbase + kb * 32 + h * 8);

  f32x4 ot[16] = {};   // O^T: 16 d-tiles x (16d x 16n)

  int j_lo = 2 * i - 4; if (j_lo < 0) j_lo = 0;
  const int j_hi = 2 * i + 1;
  const float L2G = -0.04580369f;          // log2(0.96875)

  for (int j = j_lo; j <= j_hi; ++j){
    // ---- stage K tile and V^T tile (pre-swizzled source, linear LDS dest)
    {
      const u16* kbase = Kx + ((size_t)bh * 2048 + j * 64) * 256;
#pragma unroll
      for (int t = 0; t < 4; ++t){
        int s = (w * 4 + t) * 64 + lane;
        int m = s >> 5, c = s & 31;
        gload_lds16(kbase + m * 256 + ((c ^ (m & 7)) * 8),
                    (char*)ldsK + (w * 4 + t) * 1024);
      }
      const u16* vbase = VT + (size_t)bh * DMODEL * 2048 + j * 64;
#pragma unroll
      for (int t = 0; t < 4; ++t){
        int s = (w * 4 + t) * 64 + lane;
        int d = s >> 3, c = s & 7;
        gload_lds16(vbase + (size_t)d * 2048 + ((c ^ (d & 7)) * 8),
                    (char*)ldsV + (w * 4 + t) * 1024);
      }
    }
    __syncthreads();

    if (i * 128 + w * 16 + 15 >= j * 64){     // wave has any unmasked pairs
      // ---- S^T = K · Q^T  (4 m-tiles x K=256)
      f32x4 sacc[4] = {};
#pragma unroll
      for (int kb = 0; kb < 8; ++kb){
#pragma unroll
        for (int mt = 0; mt < 4; ++mt){
          int m = mt * 16 + l15;
          int chunk = kb * 4 + h;
          bf16x8 a = *(const bf16x8*)((const char*)ldsK + m * 512 +
                                      ((chunk ^ (m & 7)) * 16));
          sacc[mt] = __builtin_amdgcn_mfma_f32_16x16x32_bf16(
              a, q[kb], sacc[mt], 0, 0, 0);
        }
      }
      // ---- decay weight + pack to bf16 pairs (per group of 4 m)
      u32 dA[4], dB[4];
#pragma unroll
      for (int mt = 0; mt < 4; ++mt){
        int m0 = j * 64 + mt * 16 + h * 4;
        int dl = n_g - m0;
        float v0 = (dl     >= 0) ? sacc[mt].x * exp2f((float)(dl    ) * L2G) : 0.0f;
        float v1 = (dl - 1 >= 0) ? sacc[mt].y * exp2f((float)(dl - 1) * L2G) : 0.0f;
        float v2 = (dl - 2 >= 0) ? sacc[mt].z * exp2f((float)(dl - 2) * L2G) : 0.0f;
        float v3 = (dl - 3 >= 0) ? sacc[mt].w * exp2f((float)(dl - 3) * L2G) : 0.0f;
        dA[mt] = (u32)f2bf(v0) | ((u32)f2bf(v1) << 16);
        dB[mt] = (u32)f2bf(v2) | ((u32)f2bf(v3) << 16);
      }
      // ---- build PV B-frags in-register (shuffle S^T C-layout -> B-layout)
      int s0 = l15 + 32 * (h & 1);
      int s1 = s0 + 16;
      bool lo = (h < 2);
#pragma unroll
      for (int kt = 0; kt < 2; ++kt){
        u32 a0 = (u32)__shfl((int)dA[2 * kt],     s0, 64);
        u32 a1 = (u32)__shfl((int)dA[2 * kt + 1], s0, 64);
        u32 b0 = (u32)__shfl((int)dB[2 * kt],     s0, 64);
        u32 b1 = (u32)__shfl((int)dB[2 * kt + 1], s0, 64);
        u32 a2 = (u32)__shfl((int)dA[2 * kt],     s1, 64);
        u32 a3 = (u32)__shfl((int)dA[2 * kt + 1], s1, 64);
        u32 b2 = (u32)__shfl((int)dB[2 * kt],     s1, 64);
        u32 b3 = (u32)__shfl((int)dB[2 * kt + 1], s1, 64);
        union { u32 u[4]; bf16x8 v; } uu;
        uu.u[0] = lo ? a0 : a1;
        uu.u[1] = lo ? b0 : b1;
        uu.u[2] = lo ? a2 : a3;
        uu.u[3] = lo ? b2 : b3;
        bf16x8 bfrag = uu.v;
        // ---- O^T += V^T · P^T
#pragma unroll
        for (int dt = 0; dt < 16; ++dt){
          int d = dt * 16 + l15;
          int chunk = kt * 4 + h;
          bf16x8 a = *(const bf16x8*)((const char*)ldsV + d * 128 +
                                      ((chunk ^ (d & 7)) * 16));
          ot[dt] = __builtin_amdgcn_mfma_f32_16x16x32_bf16(
              a, bfrag, ot[dt], 0, 0, 0);
        }
      }
    }
    __syncthreads();
  }

  // ---- write O (f32): lane holds 4 consecutive d at fixed n -> float4
  float* obase = out + ((size_t)bh * 2048 + n_g) * 256;
#pragma unroll
  for (int dt = 0; dt < 16; ++dt)
    *(f32x4*)(obase + dt * 16 + h * 4) = ot[dt];
}

// ---------------- launch ----------------
extern "C" void kernel_launch(void* const* d_in, const int* in_sizes, int n_in,
                              void* d_out, int out_size, void* d_ws, size_t ws_size,
                              hipStream_t stream)
{
  (void)in_sizes; (void)n_in; (void)out_size; (void)ws_size;
  const float* X  = (const float*)d_in[0];
  const float* WQ = (const float*)d_in[1];
  const float* WK = (const float*)d_in[2];
  const float* WV = (const float*)d_in[3];
  float* out = (float*)d_out;

  char* ws = (char*)d_ws;
  float* tqc = (float*)ws;                       // 4 x 1 MiB tables
  float* tqs = tqc + 262144;
  float* tkc = tqs + 262144;
  float* tks = tkc + 262144;
  u16* wt = (u16*)(ws + (4u << 20));             // 384 KiB
  u16* qx = (u16*)(ws + 4718592);                // 32 MiB
  u16* kx = (u16*)(ws + 38273024);               // 32 MiB
  u16* vt = (u16*)(ws + 71827456);               // 32 MiB  (end ~100.5 MiB)

  k_tables<<<dim3(1024), dim3(256), 0, stream>>>(tqc, tqs, tkc, tks);
  k_wt<<<dim3(768), dim3(256), 0, stream>>>(WQ, WK, WV, wt);
  k_proj<<<dim3(512, 3), dim3(512), 0, stream>>>(X, wt, tqc, tqs, tkc, tks,
                                                 qx, kx, vt);
  k_attn<<<dim3(512), dim3(512), 0, stream>>>(qx, kx, vt, out);
}

// Round 2
// 171.994 us; speedup vs baseline: 1.0461x; 1.0461x over previous
//
#include <hip/hip_runtime.h>
#include <stdint.h>

typedef unsigned short u16;
typedef unsigned int   u32;
typedef __attribute__((ext_vector_type(8))) short  bf16x8;
typedef __attribute__((ext_vector_type(4))) float  f32x4;
typedef __attribute__((ext_vector_type(4))) u32    u32x4;
typedef __attribute__((ext_vector_type(2))) u32    u32x2;

#define L_SEQ 2048
#define DMODEL 256
// B*H = 32, rows = 65536

// round-to-nearest-even f32 -> bf16
__device__ __forceinline__ u16 f2bf(float x){
  u32 u = __float_as_uint(x);
  return (u16)((u + 0x7FFFu + ((u >> 16) & 1u)) >> 16);
}

__device__ __forceinline__ u32 pack2(float a, float b){
  return (u32)f2bf(a) | ((u32)f2bf(b) << 16);
}

__device__ __forceinline__ void gload_lds16(const void* g, void* l){
  __builtin_amdgcn_global_load_lds(
      (const __attribute__((address_space(1))) u32*)g,
      (__attribute__((address_space(3))) u32*)l, 16, 0, 0);
}

// ---------------- xPos tables: packed (c,s) float2, [pos][hi=128] ----------
__global__ void k_tables(float2* __restrict__ tq2, float2* __restrict__ tk2){
  int idx = blockIdx.x * 256 + threadIdx.x;     // 2048*128 = 262144
  int n = idx >> 7, hi = idx & 127;
  float fn = (float)n, fi = (float)hi;
  float invf = exp2f(-(fi * (1.0f/128.0f)) * 13.2877124f);   // 10000^(-hi/128)
  float ang = fn * invf;
  float s = sinf(ang), c = cosf(ang);
  float sv = (2.0f * fi + 102.4f) * (1.0f / 358.4f);
  float sc = exp2f((fn * (1.0f/512.0f)) * log2f(sv));
  float2 q; q.x = c * sc;  q.y = s * sc;
  tq2[idx] = q;
  float inv = 1.0f / sc;
  float2 k; k.x = c * inv; k.y = s * inv;
  tk2[idx] = k;
}

// ---------------- W^T bf16: wt[w][c][k] = W_w[k][c] ----------------
__global__ void k_wt(const float* __restrict__ wq, const float* __restrict__ wk,
                     const float* __restrict__ wv, u16* __restrict__ wt){
  int idx = blockIdx.x * 256 + threadIdx.x;     // 3*65536
  int w = idx >> 16, r = idx & 65535;
  int c = r >> 8, k = r & 255;
  const float* src = (w == 0) ? wq : ((w == 1) ? wk : wv);
  wt[idx] = f2bf(src[k * 256 + c]);
}

// ---------------- fused QKV projection + xPos (+ V transpose) -------------
// grid 512 row-tiles, block 512 (8 waves). Tile: 128 rows x 256 cols, K=256.
// One X staging, three GEMMs. Q/K computed TRANSPOSED (mfma(W,X)) so each
// lane owns 4 consecutive d at fixed pos -> in-lane rotation, 8B stores.
__global__ __launch_bounds__(512, 4) void k_proj(
    const float* __restrict__ X, const u16* __restrict__ Wt,
    const float2* __restrict__ tq2, const float2* __restrict__ tk2,
    u16* __restrict__ Qx, u16* __restrict__ Kx, u16* __restrict__ VT)
{
  __shared__ u16 ldsX[128 * 256];               // 64 KiB, chunk-swizzled
  const int rt = blockIdx.x;
  const int tid = threadIdx.x;
  const int lane = tid & 63, w = tid >> 6;
  const int h = lane >> 4, l15 = lane & 15;
  const int row0 = rt * 128;
  const int bh = row0 >> 11;                    // 16 row-tiles per (b,h)

  // ---- stage X tile as bf16, fully-coalesced reads (1KB/wave/inst)
  {
    const float4* Xp = (const float4*)(X + (size_t)row0 * 256);
#pragma unroll
    for (int i = 0; i < 16; ++i){
      float4 a = Xp[i * 512 + tid];
      int r = i * 8 + w;                        // row of this wave's chunk
      int chunk = lane >> 1;
      int sw = chunk ^ (r & 7);
      u32x2 p; p.x = pack2(a.x, a.y); p.y = pack2(a.z, a.w);
      *(u32x2*)((char*)ldsX + r * 512 + sw * 16 + (lane & 1) * 8) = p;
    }
  }
  __syncthreads();

  const int wr = w >> 2, wc = w & 3;            // n-half, c-quarter

#pragma unroll
  for (int wsel = 0; wsel < 3; ++wsel){
    f32x4 acc[4][4] = {};
    const u16* wbase = Wt + wsel * 65536;

#pragma unroll
    for (int kb = 0; kb < 8; ++kb){
      bf16x8 xf[4], wf[4];
#pragma unroll
      for (int b = 0; b < 4; ++b){
        int r = wr * 64 + b * 16 + l15;
        int sw = (kb * 4 + h) ^ (r & 7);
        xf[b] = *(const bf16x8*)((const char*)ldsX + r * 512 + sw * 16);
      }
#pragma unroll
      for (int a = 0; a < 4; ++a){
        int c = wc * 64 + a * 16 + l15;
        wf[a] = *(const bf16x8*)(wbase + c * 256 + kb * 32 + h * 8);
      }
      if (wsel < 2){
#pragma unroll
        for (int a = 0; a < 4; ++a)
#pragma unroll
          for (int b = 0; b < 4; ++b)
            acc[a][b] = __builtin_amdgcn_mfma_f32_16x16x32_bf16(
                wf[a], xf[b], acc[a][b], 0, 0, 0);
      } else {
#pragma unroll
        for (int a = 0; a < 4; ++a)
#pragma unroll
          for (int b = 0; b < 4; ++b)
            acc[a][b] = __builtin_amdgcn_mfma_f32_16x16x32_bf16(
                xf[a], wf[b], acc[a][b], 0, 0, 0);
      }
    }

    if (wsel == 2){
      // V: acc[nti][cti]; lane holds 4 consecutive pos at fixed d
#pragma unroll
      for (int a = 0; a < 4; ++a){
        int pos0 = (row0 + wr * 64 + a * 16 + h * 4) & 2047;
#pragma unroll
        for (int b = 0; b < 4; ++b){
          int d = wc * 64 + b * 16 + l15;
          f32x4 v = acc[a][b];
          u32x2 p; p.x = pack2(v.x, v.y); p.y = pack2(v.z, v.w);
          *(u32x2*)(VT + ((size_t)bh * DMODEL + d) * 2048 + pos0) = p;
        }
      }
    } else {
      // Q/K: acc[cti][nti]; lane holds 4 consecutive d at fixed pos
      const float2* tt = (wsel == 0) ? tq2 : tk2;
      u16* Od = (wsel == 0) ? Qx : Kx;
#pragma unroll
      for (int a = 0; a < 4; ++a){
        int d0 = wc * 64 + a * 16 + h * 4;      // 4-aligned
#pragma unroll
        for (int b = 0; b < 4; ++b){
          int n = row0 + wr * 64 + b * 16 + l15;
          int pos = n & 2047;
          f32x4 v = acc[a][b];
          float4 t = *(const float4*)(tt + pos * 128 + (d0 >> 1));
          float y0 = v.x * t.x - v.y * t.y;     // even d: x*c - x(d+1)*s
          float y1 = v.y * t.x + v.x * t.y;     // odd d:  x*c + x(d-1)*s
          float y2 = v.z * t.z - v.w * t.w;
          float y3 = v.w * t.z + v.z * t.w;
          u32x2 p; p.x = pack2(y0, y1); p.y = pack2(y2, y3);
          *(u32x2*)(Od + (size_t)n * 256 + d0) = p;
        }
      }
    }
  }
}

// ---------------- banded decayed attention ----------------
// grid 512 = 32 bh * 16 n-chunks(128). block 512 (8 waves x 16 rows).
__global__ __launch_bounds__(512) void k_attn(
    const u16* __restrict__ Qx, const u16* __restrict__ Kx,
    const u16* __restrict__ VT, float* __restrict__ out)
{
  __shared__ char smem[65536];
  u16* ldsK = (u16*)smem;                 // [64 m][256 d] bf16, swizzled
  u16* ldsV = (u16*)(smem + 32768);       // [256 d][64 m] bf16, swizzled

  const int bid = blockIdx.x;
  const int bh = bid >> 4, i = bid & 15;
  const int tid = threadIdx.x;
  const int lane = tid & 63, w = tid >> 6;
  const int h = lane >> 4, l15 = lane & 15;
  const int n_g = i * 128 + w * 16 + l15;

  // Q B-fragments (k-contiguous from row n_g)
  bf16x8 q[8];
  const u16* qbase = Qx + ((size_t)bh * 2048 + n_g) * 256;
#pragma unroll
  for (int kb = 0; kb < 8; ++kb)
    q[kb] = *(const bf16x8*)(qbase + kb * 32 + h * 8);

  f32x4 ot[16] = {};   // O^T: 16 d-tiles x (16d x 16n)

  int j_lo = 2 * i - 4; if (j_lo < 0) j_lo = 0;
  const int j_hi = 2 * i + 1;
  const float L2G = -0.04580369f;          // log2(0.96875)

  for (int j = j_lo; j <= j_hi; ++j){
    // ---- stage K tile and V^T tile (pre-swizzled source, linear LDS dest)
    {
      const u16* kbase = Kx + ((size_t)bh * 2048 + j * 64) * 256;
#pragma unroll
      for (int t = 0; t < 4; ++t){
        int s = (w * 4 + t) * 64 + lane;
        int m = s >> 5, c = s & 31;
        gload_lds16(kbase + m * 256 + ((c ^ (m & 7)) * 8),
                    (char*)ldsK + (w * 4 + t) * 1024);
      }
      const u16* vbase = VT + (size_t)bh * DMODEL * 2048 + j * 64;
#pragma unroll
      for (int t = 0; t < 4; ++t){
        int s = (w * 4 + t) * 64 + lane;
        int d = s >> 3, c = s & 7;
        gload_lds16(vbase + (size_t)d * 2048 + ((c ^ (d & 7)) * 8),
                    (char*)ldsV + (w * 4 + t) * 1024);
      }
    }
    __syncthreads();

    if (i * 128 + w * 16 + 15 >= j * 64){     // wave has any unmasked pairs
      // ---- S^T = K · Q^T  (4 m-tiles x K=256)
      f32x4 sacc[4] = {};
#pragma unroll
      for (int kb = 0; kb < 8; ++kb){
#pragma unroll
        for (int mt = 0; mt < 4; ++mt){
          int m = mt * 16 + l15;
          int chunk = kb * 4 + h;
          bf16x8 a = *(const bf16x8*)((const char*)ldsK + m * 512 +
                                      ((chunk ^ (m & 7)) * 16));
          sacc[mt] = __builtin_amdgcn_mfma_f32_16x16x32_bf16(
              a, q[kb], sacc[mt], 0, 0, 0);
        }
      }
      // ---- decay weight + pack to bf16 pairs (per group of 4 m)
      u32 dA[4], dB[4];
#pragma unroll
      for (int mt = 0; mt < 4; ++mt){
        int m0 = j * 64 + mt * 16 + h * 4;
        int dl = n_g - m0;
        float v0 = (dl     >= 0) ? sacc[mt].x * exp2f((float)(dl    ) * L2G) : 0.0f;
        float v1 = (dl - 1 >= 0) ? sacc[mt].y * exp2f((float)(dl - 1) * L2G) : 0.0f;
        float v2 = (dl - 2 >= 0) ? sacc[mt].z * exp2f((float)(dl - 2) * L2G) : 0.0f;
        float v3 = (dl - 3 >= 0) ? sacc[mt].w * exp2f((float)(dl - 3) * L2G) : 0.0f;
        dA[mt] = pack2(v0, v1);
        dB[mt] = pack2(v2, v3);
      }
      // ---- build PV B-frags in-register (shuffle S^T C-layout -> B-layout)
      int s0 = l15 + 32 * (h & 1);
      int s1 = s0 + 16;
      bool lo = (h < 2);
#pragma unroll
      for (int kt = 0; kt < 2; ++kt){
        u32 a0 = (u32)__shfl((int)dA[2 * kt],     s0, 64);
        u32 a1 = (u32)__shfl((int)dA[2 * kt + 1], s0, 64);
        u32 b0 = (u32)__shfl((int)dB[2 * kt],     s0, 64);
        u32 b1 = (u32)__shfl((int)dB[2 * kt + 1], s0, 64);
        u32 a2 = (u32)__shfl((int)dA[2 * kt],     s1, 64);
        u32 a3 = (u32)__shfl((int)dA[2 * kt + 1], s1, 64);
        u32 b2 = (u32)__shfl((int)dB[2 * kt],     s1, 64);
        u32 b3 = (u32)__shfl((int)dB[2 * kt + 1], s1, 64);
        union { u32 u[4]; bf16x8 v; } uu;
        uu.u[0] = lo ? a0 : a1;
        uu.u[1] = lo ? b0 : b1;
        uu.u[2] = lo ? a2 : a3;
        uu.u[3] = lo ? b2 : b3;
        bf16x8 bfrag = uu.v;
        // ---- O^T += V^T · P^T
#pragma unroll
        for (int dt = 0; dt < 16; ++dt){
          int d = dt * 16 + l15;
          int chunk = kt * 4 + h;
          bf16x8 a = *(const bf16x8*)((const char*)ldsV + d * 128 +
                                      ((chunk ^ (d & 7)) * 16));
          ot[dt] = __builtin_amdgcn_mfma_f32_16x16x32_bf16(
              a, bfrag, ot[dt], 0, 0, 0);
        }
      }
    }
    __syncthreads();
  }

  // ---- write O (f32): lane holds 4 consecutive d at fixed n -> float4
  float* obase = out + ((size_t)bh * 2048 + n_g) * 256;
#pragma unroll
  for (int dt = 0; dt < 16; ++dt)
    *(f32x4*)(obase + dt * 16 + h * 4) = ot[dt];
}

// ---------------- launch ----------------
extern "C" void kernel_launch(void* const* d_in, const int* in_sizes, int n_in,
                              void* d_out, int out_size, void* d_ws, size_t ws_size,
                              hipStream_t stream)
{
  (void)in_sizes; (void)n_in; (void)out_size; (void)ws_size;
  const float* X  = (const float*)d_in[0];
  const float* WQ = (const float*)d_in[1];
  const float* WK = (const float*)d_in[2];
  const float* WV = (const float*)d_in[3];
  float* out = (float*)d_out;

  char* ws = (char*)d_ws;
  float2* tq2 = (float2*)ws;                     // 2 MiB  [2048][128] (c,s)
  float2* tk2 = (float2*)(ws + (2u << 20));      // 2 MiB
  u16* wt = (u16*)(ws + (4u << 20));             // 384 KiB
  u16* qx = (u16*)(ws + 4718592);                // 32 MiB
  u16* kx = (u16*)(ws + 38273024);               // 32 MiB
  u16* vt = (u16*)(ws + 71827456);               // 32 MiB  (end ~100.5 MiB)

  k_tables<<<dim3(1024), dim3(256), 0, stream>>>(tq2, tk2);
  k_wt<<<dim3(768), dim3(256), 0, stream>>>(WQ, WK, WV, wt);
  k_proj<<<dim3(512), dim3(512), 0, stream>>>(X, wt, tq2, tk2, qx, kx, vt);
  k_attn<<<dim3(512), dim3(512), 0, stream>>>(qx, kx, vt, out);
}